// Round 4
// baseline (146.566 us; speedup 1.0000x reference)
//
#include <hip/hip_runtime.h>
#include <hip/hip_cooperative_groups.h>

namespace cg = cooperative_groups;

// Shapes (fixed by setup_inputs)
constexpr int N  = 4, C = 64, H = 16, W = 16;
constexpr int NF = 128;
constexpr int D  = C * 9;          // 576
constexpr float EPSF = 1e-5f;

// Single cooperative kernel, 256 blocks x 1024 threads (1 block/CU).
// Phase 1: w_t[k][f] = w[f][k];  w2f[(f,a,b)][c] = w[f][c*9+flip(a,b)]
// Phase 2: s = conv3x3(x,w) in fp64; t = 2r/(2s+eps)     (block = (n,oh,ow/4))
// Phase 3: out = x * convT3x3(t, w)                      (block = (n,h,w/4))
__global__ void __launch_bounds__(1024) k_fused(
        const float* __restrict__ x, const float* __restrict__ r,
        const float* __restrict__ w, float* __restrict__ out,
        float* __restrict__ w_t, float* __restrict__ w2f,
        float* __restrict__ t_g) {
    __shared__ double partd[4 * 7 * 128];   // 28 KB; aliased as float in phase 3
    cg::grid_group grid = cg::this_grid();
    const int bid = blockIdx.x;
    const int tid = threadIdx.x;

    // ---------------- Phase 1: weight relayout (288 elems/block each) -------
    {
        const int base = bid * 288;         // 256 * 288 = 73728 = D*NF = NF*9*C
        for (int i = tid; i < 288; i += 1024) {
            const int g = base + i;
            const int k = g / NF, f = g % NF;
            w_t[g] = w[f * D + k];
            const int c2 = g % C;
            const int t2 = g / C;
            const int ab = t2 % 9, f2 = t2 / 9;
            const int a = ab / 3, b = ab % 3;
            w2f[g] = w[f2 * D + c2 * 9 + (2 - a) * 3 + (2 - b)];
        }
    }
    grid.sync();

    // ---------------- Phase 2: fp64 conv -> t -------------------------------
    {
        const int ow0 = (bid & 3) * 4;
        const int oh  = (bid >> 2) & 15;
        const int n   = bid >> 6;
        const int f   = tid & 127;
        const int cgi = tid >> 7;           // 0..7, each handles 8 channels
        const int iw0 = ow0 - 1;

        double a0 = 0, a1 = 0, a2 = 0, a3 = 0;
        const float* __restrict__ wp = w_t + f;

        for (int ci = 0; ci < 8; ++ci) {
            const int c = cgi * 8 + ci;
            const float* xbase = x + ((n * C + c) * H) * W;
#pragma unroll
            for (int dh = 0; dh < 3; ++dh) {
                const int ih = oh - 1 + dh;
                float xr[6];
                if (ih >= 0 && ih < H) {
                    const float* xrow = xbase + ih * W;
#pragma unroll
                    for (int j = 0; j < 6; ++j) {
                        const int iw = iw0 + j;
                        xr[j] = (iw >= 0 && iw < W) ? xrow[iw] : 0.f;
                    }
                } else {
#pragma unroll
                    for (int j = 0; j < 6; ++j) xr[j] = 0.f;
                }
                double xd[6];
#pragma unroll
                for (int j = 0; j < 6; ++j) xd[j] = (double)xr[j];
                const int kbase = (c * 9 + dh * 3) * NF;
#pragma unroll
                for (int b = 0; b < 3; ++b) {
                    const double wd = (double)wp[kbase + b * NF];
                    a0 += wd * xd[b];
                    a1 += wd * xd[b + 1];
                    a2 += wd * xd[b + 2];
                    a3 += wd * xd[b + 3];
                }
            }
        }

        // partd[j][cgi-1][f]: lane-contiguous over f (2-way fp64 alias = free)
        if (cgi > 0) {
            partd[(0 * 7 + cgi - 1) * 128 + f] = a0;
            partd[(1 * 7 + cgi - 1) * 128 + f] = a1;
            partd[(2 * 7 + cgi - 1) * 128 + f] = a2;
            partd[(3 * 7 + cgi - 1) * 128 + f] = a3;
        }
        __syncthreads();
        if (cgi == 0) {
#pragma unroll
            for (int g = 0; g < 7; ++g) {
                a0 += partd[(0 * 7 + g) * 128 + f];
                a1 += partd[(1 * 7 + g) * 128 + f];
                a2 += partd[(2 * 7 + g) * 128 + f];
                a3 += partd[(3 * 7 + g) * 128 + f];
            }
            const int base = ((n * NF + f) * H + oh) * W + ow0;
            const float* rp = r + base;
            float* tp = t_g + base;
            tp[0] = (float)((2.0 * (double)rp[0]) / (2.0 * a0 + (double)EPSF));
            tp[1] = (float)((2.0 * (double)rp[1]) / (2.0 * a1 + (double)EPSF));
            tp[2] = (float)((2.0 * (double)rp[2]) / (2.0 * a2 + (double)EPSF));
            tp[3] = (float)((2.0 * (double)rp[3]) / (2.0 * a3 + (double)EPSF));
        }
    }
    grid.sync();

    // ---------------- Phase 3: convT * x -> out -----------------------------
    {
        const int w0 = (bid & 3) * 4;
        const int h  = (bid >> 2) & 15;
        const int n  = bid >> 6;
        const int c  = tid & 63;
        const int fg = tid >> 6;            // 0..15, each handles 8 filters
        const int iw0 = w0 - 1;

        float b0 = 0, b1 = 0, b2 = 0, b3 = 0;

        for (int fi = 0; fi < 8; ++fi) {
            const int f = fg * 8 + fi;
            const float* tbase = t_g + ((n * NF + f) * H) * W;
            const float* __restrict__ wfa = w2f + (f * 9) * C + c;
#pragma unroll
            for (int a = 0; a < 3; ++a) {
                const int oh2 = h - 1 + a;
                float tr[6];
                if (oh2 >= 0 && oh2 < H) {
                    const float* trow = tbase + oh2 * W;
#pragma unroll
                    for (int j = 0; j < 6; ++j) {
                        const int ow = iw0 + j;
                        tr[j] = (ow >= 0 && ow < W) ? trow[ow] : 0.f;
                    }
                } else {
#pragma unroll
                    for (int j = 0; j < 6; ++j) tr[j] = 0.f;
                }
#pragma unroll
                for (int b = 0; b < 3; ++b) {
                    const float wv = wfa[(a * 3 + b) * C];
                    b0 += wv * tr[b];
                    b1 += wv * tr[b + 1];
                    b2 += wv * tr[b + 2];
                    b3 += wv * tr[b + 3];
                }
            }
        }

        // fpart[j][fg-1][c]: lane-contiguous over c, conflict-free
        float* fpart = (float*)partd;       // 15*64*4 floats = 15 KB <= 28 KB
        if (fg > 0) {
            fpart[(0 * 15 + fg - 1) * 64 + c] = b0;
            fpart[(1 * 15 + fg - 1) * 64 + c] = b1;
            fpart[(2 * 15 + fg - 1) * 64 + c] = b2;
            fpart[(3 * 15 + fg - 1) * 64 + c] = b3;
        }
        __syncthreads();
        if (fg == 0) {
#pragma unroll
            for (int g = 0; g < 15; ++g) {
                b0 += fpart[(0 * 15 + g) * 64 + c];
                b1 += fpart[(1 * 15 + g) * 64 + c];
                b2 += fpart[(2 * 15 + g) * 64 + c];
                b3 += fpart[(3 * 15 + g) * 64 + c];
            }
            const int base = ((n * C + c) * H + h) * W + w0;
            out[base + 0] = x[base + 0] * b0;
            out[base + 1] = x[base + 1] * b1;
            out[base + 2] = x[base + 2] * b2;
            out[base + 3] = x[base + 3] * b3;
        }
    }
}

// ---------------------------------------------------------------------------
extern "C" void kernel_launch(void* const* d_in, const int* in_sizes, int n_in,
                              void* d_out, int out_size, void* d_ws, size_t ws_size,
                              hipStream_t stream) {
    const float* x = (const float*)d_in[0];   // (4,64,16,16)
    const float* r = (const float*)d_in[1];   // (4,128,16,16)
    const float* w = (const float*)d_in[2];   // (128,64,3,3)
    float* out = (float*)d_out;               // (4,64,16,16)

    float* ws   = (float*)d_ws;
    float* w_t  = ws;                         // D*NF   = 73728
    float* w2f  = w_t + D * NF;               // NF*9*C = 73728
    float* t_g  = w2f + NF * 9 * C;           // N*NF*H*W = 131072

    void* args[] = {(void*)&x, (void*)&r, (void*)&w, (void*)&out,
                    (void*)&w_t, (void*)&w2f, (void*)&t_g};
    hipLaunchCooperativeKernel((const void*)k_fused, dim3(256), dim3(1024),
                               args, 0, stream);
}

// Round 5
// 73.475 us; speedup vs baseline: 1.9948x; 1.9948x over previous
//
#include <hip/hip_runtime.h>

// Shapes (fixed by setup_inputs)
constexpr int N  = 4, C = 64, H = 16, W = 16;
constexpr int NF = 128;
constexpr int D  = C * 9;          // 576
constexpr float EPSF = 1e-5f;

// ---------------------------------------------------------------------------
// Prep: w_t4 float4-layout: elem[(k4*128 + f)*4 + j] = w[f][k4*4 + j]
//       w2f4 float4-layout: elem[((fq*9+ab)*64 + c)*4 + j]
//                           = w[fq*4+j][c*9 + flip(ab)]
// Both 73728 floats; one thread writes one element of each.
// ---------------------------------------------------------------------------
__global__ void k_prep(const float* __restrict__ w,
                       float* __restrict__ w_t4, float* __restrict__ w2f4) {
    const int o = blockIdx.x * 256 + threadIdx.x;
    if (o >= 73728) return;
    const int j = o & 3;
    {
        const int f = (o >> 2) & 127, k4 = o >> 9;
        w_t4[o] = w[f * D + k4 * 4 + j];
    }
    {
        const int c = (o >> 2) & 63, rest = o >> 8;
        const int ab = rest % 9, fq = rest / 9;
        const int a = ab / 3, b = ab % 3;
        w2f4[o] = w[(fq * 4 + j) * D + c * 9 + (2 - a) * 3 + (2 - b)];
    }
}

// ---------------------------------------------------------------------------
// K1: s = conv3x3(x,w) fp64; t = 2r/(2s+eps)
// Grid 256 = (n, oh, ow/4).  Threads 1024 = f(128) x cg(8); cg owns 8 channels
// = 72 taps = 18 float4 w loads (coalesced over f).  x slab staged in LDS as
// fp64 (lane reads are broadcast).  Fully unrolled.
// ---------------------------------------------------------------------------
__global__ void __launch_bounds__(1024) k_conv_t(
        const float* __restrict__ x, const float4* __restrict__ w_t4,
        const float* __restrict__ r, float* __restrict__ t_g) {
    __shared__ double xl[C * 18];          // 9.2 KB: [c][dh*6+dw]
    __shared__ double partd[4 * 7 * 128];  // 28 KB

    const int bid = blockIdx.x;
    const int ow0 = (bid & 3) * 4;
    const int oh  = (bid >> 2) & 15;
    const int n   = bid >> 6;
    const int tid = threadIdx.x;
    const int f   = tid & 127;
    const int cg  = tid >> 7;              // 0..7

    for (int idx = tid; idx < C * 18; idx += 1024) {
        const int c = idx / 18, rem = idx % 18;
        const int dh = rem / 6, dw = rem % 6;
        const int ih = oh - 1 + dh, iw = ow0 - 1 + dw;
        float v = 0.f;
        if (ih >= 0 && ih < H && iw >= 0 && iw < W)
            v = x[((n * C + c) * H + ih) * W + iw];
        xl[idx] = (double)v;
    }
    __syncthreads();

    double a0 = 0, a1 = 0, a2 = 0, a3 = 0;
    const int c0 = cg * 8;
    const float4* __restrict__ wp = w_t4 + cg * 18 * 128 + f;
#pragma unroll
    for (int i = 0; i < 18; ++i) {
        const float4 wv = wp[i * 128];
        const float wf[4] = {wv.x, wv.y, wv.z, wv.w};
#pragma unroll
        for (int j = 0; j < 4; ++j) {
            const int kl = i * 4 + j;              // 0..71, compile-time
            const int cl = kl / 9, tap = kl % 9;
            const int dh = tap / 3, db = tap % 3;
            const double wd = (double)wf[j];
            const double* xv = xl + (c0 + cl) * 18 + dh * 6 + db;
            a0 += wd * xv[0];
            a1 += wd * xv[1];
            a2 += wd * xv[2];
            a3 += wd * xv[3];
        }
    }

    if (cg > 0) {
        partd[(0 * 7 + cg - 1) * 128 + f] = a0;
        partd[(1 * 7 + cg - 1) * 128 + f] = a1;
        partd[(2 * 7 + cg - 1) * 128 + f] = a2;
        partd[(3 * 7 + cg - 1) * 128 + f] = a3;
    }
    __syncthreads();
    if (cg == 0) {
#pragma unroll
        for (int g = 0; g < 7; ++g) {
            a0 += partd[(0 * 7 + g) * 128 + f];
            a1 += partd[(1 * 7 + g) * 128 + f];
            a2 += partd[(2 * 7 + g) * 128 + f];
            a3 += partd[(3 * 7 + g) * 128 + f];
        }
        const int base = ((n * NF + f) * H + oh) * W + ow0;
        const float* rp = r + base;
        float* tp = t_g + base;
        tp[0] = (float)((2.0 * (double)rp[0]) / (2.0 * a0 + (double)EPSF));
        tp[1] = (float)((2.0 * (double)rp[1]) / (2.0 * a1 + (double)EPSF));
        tp[2] = (float)((2.0 * (double)rp[2]) / (2.0 * a2 + (double)EPSF));
        tp[3] = (float)((2.0 * (double)rp[3]) / (2.0 * a3 + (double)EPSF));
    }
}

// ---------------------------------------------------------------------------
// K2: out = x * convT3x3(t, w)
// Grid 256 = (n, h, w/4).  Threads 1024 = c(64) x fg(16); fg owns 8 filters
// = 2 float4-quads x 9 taps (w2f4 coalesced over c).  t slab staged in LDS
// ([f][a][ww], ww = ow+1).  Fully unrolled.
// ---------------------------------------------------------------------------
__global__ void __launch_bounds__(1024) k_convT_out(
        const float* __restrict__ x, const float4* __restrict__ w2f4,
        const float* __restrict__ t_g, float* __restrict__ out) {
    __shared__ float tl[NF * 54];          // 27.6 KB
    __shared__ float fpart[4 * 15 * 64];   // 15.4 KB

    const int bid = blockIdx.x;
    const int w0  = (bid & 3) * 4;
    const int h   = (bid >> 2) & 15;
    const int n   = bid >> 6;
    const int tid = threadIdx.x;
    const int c   = tid & 63;
    const int fg  = tid >> 6;              // 0..15

    for (int idx = tid; idx < NF * 54; idx += 1024) {
        const int ff = idx / 54, rem = idx % 54;
        const int a = rem / 18, ww = rem % 18;
        const int oh2 = h - 1 + a, ow = ww - 1;
        float v = 0.f;
        if (oh2 >= 0 && oh2 < H && ow >= 0 && ow < W)
            v = t_g[((n * NF + ff) * H + oh2) * W + ow];
        tl[idx] = v;
    }
    __syncthreads();

    float b0 = 0, b1 = 0, b2 = 0, b3 = 0;
#pragma unroll
    for (int q = 0; q < 2; ++q) {
        const int fq = fg * 2 + q;
        const float4* __restrict__ wp = w2f4 + fq * 9 * 64 + c;
#pragma unroll
        for (int ab = 0; ab < 9; ++ab) {
            const int a = ab / 3, b = ab % 3;
            const float4 wv = wp[ab * 64];
            const float wf[4] = {wv.x, wv.y, wv.z, wv.w};
#pragma unroll
            for (int j = 0; j < 4; ++j) {
                const float* tv = tl + (fq * 4 + j) * 54 + a * 18 + w0 + b;
                b0 += wf[j] * tv[0];
                b1 += wf[j] * tv[1];
                b2 += wf[j] * tv[2];
                b3 += wf[j] * tv[3];
            }
        }
    }

    if (fg > 0) {
        fpart[(0 * 15 + fg - 1) * 64 + c] = b0;
        fpart[(1 * 15 + fg - 1) * 64 + c] = b1;
        fpart[(2 * 15 + fg - 1) * 64 + c] = b2;
        fpart[(3 * 15 + fg - 1) * 64 + c] = b3;
    }
    __syncthreads();
    if (fg == 0) {
#pragma unroll
        for (int g = 0; g < 15; ++g) {
            b0 += fpart[(0 * 15 + g) * 64 + c];
            b1 += fpart[(1 * 15 + g) * 64 + c];
            b2 += fpart[(2 * 15 + g) * 64 + c];
            b3 += fpart[(3 * 15 + g) * 64 + c];
        }
        const int base = ((n * C + c) * H + h) * W + w0;
        out[base + 0] = x[base + 0] * b0;
        out[base + 1] = x[base + 1] * b1;
        out[base + 2] = x[base + 2] * b2;
        out[base + 3] = x[base + 3] * b3;
    }
}

// ---------------------------------------------------------------------------
extern "C" void kernel_launch(void* const* d_in, const int* in_sizes, int n_in,
                              void* d_out, int out_size, void* d_ws, size_t ws_size,
                              hipStream_t stream) {
    const float* x = (const float*)d_in[0];   // (4,64,16,16)
    const float* r = (const float*)d_in[1];   // (4,128,16,16)
    const float* w = (const float*)d_in[2];   // (128,64,3,3)
    float* out = (float*)d_out;               // (4,64,16,16)

    float* ws    = (float*)d_ws;
    float* w_t4  = ws;                        // 73728 floats
    float* w2f4  = w_t4 + 73728;              // 73728 floats (16B-aligned)
    float* t_g   = w2f4 + 73728;              // 131072 floats

    k_prep<<<288, 256, 0, stream>>>(w, w_t4, w2f4);
    k_conv_t<<<256, 1024, 0, stream>>>(x, (const float4*)w_t4, r, t_g);
    k_convT_out<<<256, 1024, 0, stream>>>(x, (const float4*)w2f4, t_g, out);
}